// Round 12
// baseline (332.409 us; speedup 1.0000x reference)
//
#include <hip/hip_runtime.h>
#include <stdint.h>

// EfficientSelfAttention on MI355X (gfx950). External I/O FP32; internals bf16
// MFMA. B=4, T=4096, D=1024, H=8, Dh=128. Scratch in __device__ globals.
// R18: fragment-linear weights. prep permutes Wq/Wk/Wv into g_WF so that a
//      wave's MFMA B-fragment is ONE coalesced 1KB global load (base+lane*16B)
//      from L2-resident weights. kva/qy load B direct to VGPR: all B LDS
//      staging + vmcnt + ds_reads deleted (per tile: 8->4 stage loads,
//      24->16KB/wave LDS reads). WF[which] elem W[kd][f] at
//      ((((f>>7)*16+(kd>>6))*2+((kd>>5)&1))*8+((f>>4)&7))*512
//        + ((kd>>3)&3)*128 + (f&15)*8 + (kd&7)
//      == frag(head,tile,ks,fb) base + lane*8 elems for lane=(q*16+r).
//      R17's fusion (kva = k/v-proj + local att, no ekT/vvT in HBM) kept.

typedef unsigned short u16;
typedef __attribute__((ext_vector_type(8))) short bf16x8;
typedef __attribute__((ext_vector_type(4))) float f32x4;

// ------------------------------------------------------- device workspace
__device__ u16 g_WF[3][1024 * 1024];   // 6 MiB: Wq,Wk,Wv fragment-linear bf16
__device__ u16 g_xn[16777216];         // 32 MiB
__device__ float g_attp[8388608];      // 32 MiB  [tt*32+bh][d*128+l], 16 chunks
__device__ u16 g_attT[524288];         // 1 MiB   [bh][l*128+d]
__device__ float g_Z[4096];            //         [b*1024+d]
__device__ int g_mflag[64];            // any(mask>0.5) per 256-token block

__device__ __forceinline__ float b2f(u16 u) {
  union { unsigned int i; float f; } c;
  c.i = ((unsigned int)u) << 16;
  return c.f;
}
__device__ __forceinline__ u16 f2b(float f) {
  union { float f; unsigned int i; } c;
  c.f = f;
  unsigned int r = c.i + 0x7fffu + ((c.i >> 16) & 1u);
  return (u16)(r >> 16);
}

__device__ __forceinline__ void gload16(const void* g, void* l) {
  __builtin_amdgcn_global_load_lds(
      reinterpret_cast<const __attribute__((address_space(1))) uint32_t*>(
          reinterpret_cast<uintptr_t>(g)),
      reinterpret_cast<__attribute__((address_space(3))) uint32_t*>(
          reinterpret_cast<uintptr_t>(l)),
      16, 0, 0);
}

// ---------------- A-tile [256][64]-bf16, 128B rows, chunk^(row&7) swizzle ---
// Stage: linear LDS dest (global_load_lds requirement) + inverse-swizzled
// per-lane GLOBAL source chunk. Read: swizzled ds_read. (rule #21)
__device__ __forceinline__ void stageA256(char* buf, const u16* gsrc, int h,
                                          int wave, int lane) {
#pragma unroll
  for (int i = 0; i < 2; i++) {
    const int ib = i * 64 + wave * 8;  // idx base (wave-uniform)
    const int rowb = (ib & 63) | ((ib & 64) << 1) | (h << 6);
    const int row = rowb + (lane >> 3);
    const int cc = (lane & 7) ^ (row & 7);  // inverse-swizzled source chunk
    gload16((const char*)gsrc + ((size_t)row * 1024 + cc * 8) * 2,
            buf + rowb * 128);
  }
}
// frag read: row R (includes lane&15), k-step ks: global chunk = ks*4 + q
__device__ __forceinline__ bf16x8 fragS(const char* buf, int R, int ks, int lane) {
  const int q = lane >> 4;
  return *(const bf16x8*)(buf + R * 128 + ((((ks << 2) + q) ^ (R & 7)) << 4));
}
// fragment-linear B load: frag (t, ks, fb) of matrix wf (head folded into wf).
__device__ __forceinline__ bf16x8 fragW(const u16* wf, int t, int ks, int fb,
                                        int lane) {
  return *(const bf16x8*)(wf + (size_t)(((t * 2 + ks) * 8) + fb) * 512 +
                          lane * 8);
}

// One qy ph1 K-tile, ONE phase. A staged via LDS dbuf; B (Wq) direct from WF.
template <bool ST>
__device__ __forceinline__ void tile_1ph(char* Ab, char* An, const u16* Agn,
                                         const u16* wfQ, int hbase, int t,
                                         f32x4 (&acc)[8][4], int wave, int lane,
                                         int wm, int wn) {
  if constexpr (ST) {
    stageA256(An, Agn, 0, wave, lane);
    stageA256(An, Agn, 1, wave, lane);
  }
  bf16x8 a[4][2], b[4][2];
#pragma unroll
  for (int cf = 0; cf < 4; cf++) {
    const int fc = wn * 4 + cf;              // slab-relative 16-feat block
    const u16* wf = wfQ + (size_t)(hbase + (fc >> 3)) * 131072;
#pragma unroll
    for (int ks = 0; ks < 2; ks++) b[cf][ks] = fragW(wf, t, ks, fc & 7, lane);
  }
#pragma unroll
  for (int rf = 0; rf < 4; rf++) {
    const int R = wm * 128 + rf * 16 + (lane & 15);
#pragma unroll
    for (int ks = 0; ks < 2; ks++) a[rf][ks] = fragS(Ab, R, ks, lane);
  }
  __builtin_amdgcn_s_setprio(1);
#pragma unroll
  for (int rf = 0; rf < 4; rf++)
#pragma unroll
    for (int cf = 0; cf < 4; cf++)
#pragma unroll
      for (int ks = 0; ks < 2; ks++)
        acc[rf][cf] = __builtin_amdgcn_mfma_f32_16x16x32_bf16(
            a[rf][ks], b[cf][ks], acc[rf][cf], 0, 0, 0);
  bf16x8 a2[4][2];
#pragma unroll
  for (int rf = 0; rf < 4; rf++) {
    const int R = wm * 128 + 64 + rf * 16 + (lane & 15);
#pragma unroll
    for (int ks = 0; ks < 2; ks++) a2[rf][ks] = fragS(Ab, R, ks, lane);
  }
#pragma unroll
  for (int rf = 0; rf < 4; rf++)
#pragma unroll
    for (int cf = 0; cf < 4; cf++)
#pragma unroll
      for (int ks = 0; ks < 2; ks++)
        acc[4 + rf][cf] = __builtin_amdgcn_mfma_f32_16x16x32_bf16(
            a2[rf][ks], b[cf][ks], acc[4 + rf][cf], 0, 0, 0);
  __builtin_amdgcn_s_setprio(0);
  if constexpr (ST) asm volatile("s_waitcnt vmcnt(0)" ::: "memory");
  __builtin_amdgcn_s_barrier();
  __builtin_amdgcn_sched_barrier(0);
}

// kva K-tile: A[256][64] LDS-staged; Bk/Bv direct from WF (head folded in).
// Per wave 128tok x 32feat for EACH of ek/vv; 64 MFMA/wave/tile.
template <bool ST>
__device__ __forceinline__ void tile_kv(char* Ab, char* An, const u16* Agn,
                                        const u16* wfK, const u16* wfV, int t,
                                        f32x4 (&ae)[8][2], f32x4 (&av)[8][2],
                                        int wave, int lane, int wm, int wn) {
  if constexpr (ST) {
    stageA256(An, Agn, 0, wave, lane);
    stageA256(An, Agn, 1, wave, lane);
  }
  bf16x8 bk[2][2], bv[2][2];
#pragma unroll
  for (int cf = 0; cf < 2; cf++) {
    const int fb = wn * 2 + cf;  // 16-feat block within the 128-feat head
#pragma unroll
    for (int ks = 0; ks < 2; ks++) {
      bk[cf][ks] = fragW(wfK, t, ks, fb, lane);
      bv[cf][ks] = fragW(wfV, t, ks, fb, lane);
    }
  }
  bf16x8 a[4][2];
#pragma unroll
  for (int rf = 0; rf < 4; rf++) {
    const int R = wm * 128 + rf * 16 + (lane & 15);
#pragma unroll
    for (int ks = 0; ks < 2; ks++) a[rf][ks] = fragS(Ab, R, ks, lane);
  }
  __builtin_amdgcn_s_setprio(1);
#pragma unroll
  for (int rf = 0; rf < 4; rf++)
#pragma unroll
    for (int cf = 0; cf < 2; cf++)
#pragma unroll
      for (int ks = 0; ks < 2; ks++) {
        ae[rf][cf] = __builtin_amdgcn_mfma_f32_16x16x32_bf16(
            a[rf][ks], bk[cf][ks], ae[rf][cf], 0, 0, 0);
        av[rf][cf] = __builtin_amdgcn_mfma_f32_16x16x32_bf16(
            a[rf][ks], bv[cf][ks], av[rf][cf], 0, 0, 0);
      }
  bf16x8 a2[4][2];
#pragma unroll
  for (int rf = 0; rf < 4; rf++) {
    const int R = wm * 128 + 64 + rf * 16 + (lane & 15);
#pragma unroll
    for (int ks = 0; ks < 2; ks++) a2[rf][ks] = fragS(Ab, R, ks, lane);
  }
#pragma unroll
  for (int rf = 0; rf < 4; rf++)
#pragma unroll
    for (int cf = 0; cf < 2; cf++)
#pragma unroll
      for (int ks = 0; ks < 2; ks++) {
        ae[4 + rf][cf] = __builtin_amdgcn_mfma_f32_16x16x32_bf16(
            a2[rf][ks], bk[cf][ks], ae[4 + rf][cf], 0, 0, 0);
        av[4 + rf][cf] = __builtin_amdgcn_mfma_f32_16x16x32_bf16(
            a2[rf][ks], bv[cf][ks], av[4 + rf][cf], 0, 0, 0);
      }
  __builtin_amdgcn_s_setprio(0);
  if constexpr (ST) asm volatile("s_waitcnt vmcnt(0)" ::: "memory");
  __builtin_amdgcn_s_barrier();
  __builtin_amdgcn_sched_barrier(0);
}

// ---------------------------- prep: LN (blocks 0..16383) + W permute (rest)
// Blocks 0..63 also compute g_mflag[bid] = any(mask[bid*256..+255]>0.5).
// Permute blocks write W into fragment-linear g_WF (see header comment).
__global__ __launch_bounds__(256) void prep_kernel(const float* __restrict__ x,
                                                   const float* __restrict__ gamma,
                                                   const float* __restrict__ beta,
                                                   const float* __restrict__ wq,
                                                   const float* __restrict__ wk,
                                                   const float* __restrict__ wv,
                                                   const float* __restrict__ mask) {
  __shared__ float ls[4], ls2[4];
  __shared__ u16 tile[32][33];
  __shared__ int sflag;
  const int bid = blockIdx.x;
  const int tid = threadIdx.x;
  if (bid < 16384) {
    if (bid < 16) g_Z[bid * 256 + tid] = 0.0f;  // per-launch Z reset
    if (bid < 64) {
      if (tid == 0) sflag = 0;
      __syncthreads();
      if (mask[bid * 256 + tid] > 0.5f) atomicOr(&sflag, 1);
      __syncthreads();
      if (tid == 0) g_mflag[bid] = sflag;
    }
    const int wave = tid >> 6, lane = tid & 63;
    const float* xr = x + (size_t)bid * 1024;
    float4 u = ((const float4*)xr)[tid];
    float v0 = u.x, v1 = u.y, v2 = u.z, v3 = u.w;
    float s = v0 + v1 + v2 + v3;
    float s2 = v0 * v0 + v1 * v1 + v2 * v2 + v3 * v3;
#pragma unroll
    for (int off = 32; off > 0; off >>= 1) {
      s += __shfl_down(s, off);
      s2 += __shfl_down(s2, off);
    }
    if (lane == 0) { ls[wave] = s; ls2[wave] = s2; }
    __syncthreads();
    s = ls[0] + ls[1] + ls[2] + ls[3];
    s2 = ls2[0] + ls2[1] + ls2[2] + ls2[3];
    const float mu = s * (1.0f / 1024.0f);
    const float var = fmaxf(s2 * (1.0f / 1024.0f) - mu * mu, 0.0f);
    const float rstd = rsqrtf(var + 1e-5f);
    float4 g4 = ((const float4*)gamma)[tid];
    float4 be = ((const float4*)beta)[tid];
    ushort4 o;
    o.x = f2b((v0 - mu) * rstd * g4.x + be.x);
    o.y = f2b((v1 - mu) * rstd * g4.y + be.y);
    o.z = f2b((v2 - mu) * rstd * g4.z + be.z);
    o.w = f2b((v3 - mu) * rstd * g4.w + be.w);
    *(ushort4*)(g_xn + (size_t)bid * 1024 + tid * 4) = o;
  } else {
    const int id = bid - 16384;
    const int which = id >> 10;   // 0=Wq 1=Wk 2=Wv
    const int rem = id & 1023;
    const float* src = (which == 0) ? wq : (which == 1) ? wk : wv;
    const int tx = tid & 31;
    const int ty = tid >> 5;
    const int c0 = (rem & 31) * 32, r0 = (rem >> 5) * 32;  // c=f, r=kd
#pragma unroll
    for (int i = 0; i < 4; i++)
      tile[ty + i * 8][tx] = f2b(src[(size_t)(r0 + ty + i * 8) * 1024 + c0 + tx]);
    __syncthreads();
    // write 32f x 32kd as 128 16B chunks: thread<128: f_loc=tid&31, jg=tid>>5
    if (tid < 128) {
      const int f_loc = tid & 31, jg = tid >> 5;
      const int f = c0 + f_loc, kd0 = r0 + jg * 8;
      const int h = f >> 7, fb = (f >> 4) & 7, r = f & 15;
      const int t = kd0 >> 6, ks = (kd0 >> 5) & 1, q = (kd0 >> 3) & 3;
      union { u16 u[8]; uint4 v; } pk;
#pragma unroll
      for (int j = 0; j < 8; j++) pk.u[j] = tile[jg * 8 + j][f_loc];
      const size_t off =
          ((size_t)((((h * 16 + t) * 2 + ks) * 8 + fb)) * 64 + q * 16 + r) * 8;
      *(uint4*)&g_WF[which][off] = pk.v;
    }
  }
}

// --------------------------------------------- fused K/V projection + att
// Grid 512 = 64 (b,tt) x 8 heads. L = bt + 64*h (8 same-A blocks per XCD).
// Per block: 256 tokens x head h; ek/vv -> LDS transpose -> fused Z -> local
// att GEMM -> attp chunk. Fully-masked tiles exit (attnorm skips chunks).
__global__ __launch_bounds__(512, 2) void gemm_kva(const float* __restrict__ bk,
                                                   const float* __restrict__ bv,
                                                   const float* __restrict__ mask) {
  __shared__ __align__(16) char smem[131072];
  const int tid = threadIdx.x, wave = tid >> 6, lane = tid & 63;
  const int L = blockIdx.x;
  const int bt = L & 63;           // (b,tt): b = bt>>4, tt = bt&15
  const int h = L >> 6;            // head 0..7
  const int m0 = bt * 256;
  const int b = m0 >> 12;
  const int tt = bt & 15;
  if (!g_mflag[bt]) return;        // exact-zero chunk; attnorm skips it

  const int wm = wave >> 2, wn = wave & 3;
  const u16* Ag = g_xn + (size_t)m0 * 1024;
  const u16* wfK = g_WF[1] + (size_t)h * 131072;
  const u16* wfV = g_WF[2] + (size_t)h * 131072;

  char* A0 = smem;            // 32K
  char* A1 = smem + 32768;    // 32K ; epilogue: ekT@0 64K, vvT@65536 64K

  f32x4 zero = {0.f, 0.f, 0.f, 0.f};
  f32x4 ae[8][2], av[8][2];
#pragma unroll
  for (int i = 0; i < 8; i++)
#pragma unroll
    for (int j = 0; j < 2; j++) { ae[i][j] = zero; av[i][j] = zero; }

  // prologue: stage A tile 0, full drain (once)
  stageA256(A0, Ag, 0, wave, lane);
  stageA256(A0, Ag, 1, wave, lane);
  asm volatile("s_waitcnt vmcnt(0)" ::: "memory");
  __builtin_amdgcn_s_barrier();

#pragma unroll 1
  for (int t = 0; t < 15; ++t) {
    const int p = t & 1;
    tile_kv<true>(p ? A1 : A0, p ? A0 : A1, Ag + (t + 1) * 64, wfK, wfV, t, ae,
                  av, wave, lane, wm, wn);
  }
  tile_kv<false>(A1, A0, Ag, wfK, wfV, 15, ae, av, wave, lane, wm, wn);

  // epilogue-1: bias + exp/mask, transpose into LDS (ekT, vvT), fused Z.
  u16* ekT = (u16*)smem;
  u16* vvT = (u16*)(smem + 65536);
  float fsum[2] = {0.f, 0.f};
#pragma unroll
  for (int rf = 0; rf < 8; rf++)
#pragma unroll
    for (int r = 0; r < 4; r++) {
      const int tok = wm * 128 + rf * 16 + (lane >> 4) * 4 + r;
      const float mv = mask[m0 + tok];
#pragma unroll
      for (int cf = 0; cf < 2; cf++) {
        const int feat = wn * 32 + cf * 16 + (lane & 15);  // 0..127 in-head
        const int slot = (((tok >> 3) ^ (feat & 31)) << 3) | (tok & 7);
        const float ve = ae[rf][cf][r] + bk[h * 128 + feat];
        const float oe = (mv > 0.5f) ? __expf(fminf(ve, 30.0f)) : 0.0f;
        const u16 eb = f2b(oe);
        ekT[feat * 256 + slot] = eb;
        fsum[cf] += b2f(eb);  // sum rounded values == zrow semantics
        const float vv = (av[rf][cf][r] + bv[h * 128 + feat]) * mv;
        vvT[feat * 256 + slot] = f2b(vv);
      }
    }
#pragma unroll
  for (int cf = 0; cf < 2; cf++) {
    float s = fsum[cf];
    s += __shfl_xor(s, 16);
    s += __shfl_xor(s, 32);
    if (lane < 16)
      atomicAdd(&g_Z[b * 1024 + h * 128 + wn * 32 + cf * 16 + lane], s);
  }
  __syncthreads();

  // epilogue-2: local GEMM att[d][l] = sum_t ekT[d][t]*vvT[l][t], K=256.
  f32x4 acc2[4][2];
#pragma unroll
  for (int i = 0; i < 4; i++)
#pragma unroll
    for (int j = 0; j < 2; j++) acc2[i][j] = zero;
#pragma unroll
  for (int ks = 0; ks < 8; ks++) {
    bf16x8 aF[4], bF[2];
#pragma unroll
    for (int rf = 0; rf < 4; rf++) {
      const int d = wm * 64 + rf * 16 + (lane & 15);
      aF[rf] = *(const bf16x8*)&ekT[d * 256 +
          ((((ks << 2) + (lane >> 4)) ^ (d & 31)) << 3)];
    }
#pragma unroll
    for (int cf = 0; cf < 2; cf++) {
      const int l = wn * 32 + cf * 16 + (lane & 15);
      bF[cf] = *(const bf16x8*)&vvT[l * 256 +
          ((((ks << 2) + (lane >> 4)) ^ (l & 31)) << 3)];
    }
#pragma unroll
    for (int rf = 0; rf < 4; rf++)
#pragma unroll
      for (int cf = 0; cf < 2; cf++)
        acc2[rf][cf] = __builtin_amdgcn_mfma_f32_16x16x32_bf16(
            aF[rf], bF[cf], acc2[rf][cf], 0, 0, 0);
  }

  float* op = g_attp + (size_t)(tt * 32 + b * 8 + h) * 16384;
#pragma unroll
  for (int rf = 0; rf < 4; rf++)
#pragma unroll
    for (int r = 0; r < 4; r++) {
      const int d = wm * 64 + rf * 16 + (lane >> 4) * 4 + r;
#pragma unroll
      for (int cf = 0; cf < 2; cf++) {
        const int l = wn * 32 + cf * 16 + (lane & 15);
        op[d * 128 + l] = acc2[rf][cf][r];
      }
    }
}

// ------------------------------------- reduce partials, /Z, store attT[bh][l][d]
__global__ __launch_bounds__(256) void attnorm_kernel() {
  const int bh = blockIdx.x;
  const int b = bh >> 3, h = bh & 7;
  const int tid = threadIdx.x;
  __shared__ float Zl[128];
  __shared__ int vfl[16];
  if (tid < 128) Zl[tid] = fmaxf(g_Z[b * 1024 + h * 128 + tid], 1e-30f);
  if (tid < 16) vfl[tid] = g_mflag[b * 16 + tid];
  __syncthreads();
  const int i0 = blockIdx.y * 2048;
  for (int i = i0 + tid; i < i0 + 2048; i += 256) {
    const int d = i >> 7, l = i & 127;
    float s = 0.f;
#pragma unroll
    for (int c = 0; c < 16; c++)
      if (vfl[c]) s += g_attp[((size_t)(c * 32 + bh)) * 16384 + i];
    g_attT[(size_t)bh * 16384 + l * 128 + d] = f2b(s / Zl[d]);
  }
}

// ---------------------------------------------------------- fused q + y
// 256^2 1-phase ph1 over the FULL feature dim (tile = 2 heads). Grid 256.
// ph1: q = xn @ WqT (K=1024), A via LDS dbuf, B (Wq) direct from WF.
// Epilogue-1: exp(q+bq) -> swizzled qs[256][256] in LDS + per-head row sums.
// ph2: y = P @ attT (K=128, 2 heads). Epilogue-2: out = x + y/zq.
__global__ __launch_bounds__(512, 2) void gemm_qy(const float* __restrict__ bq,
                                                  const float* __restrict__ x,
                                                  float* __restrict__ out) {
  __shared__ __align__(16) char smem[131072];
  __shared__ float zq4[4][256];
  const int tid = threadIdx.x, wave = tid >> 6, lane = tid & 63;
  const int L = blockIdx.x;
  const int g = L >> 3;
  const int mt = (L & 7) + 8 * (g >> 2);
  const int n0 = (g & 3) * 256;
  const int m0 = mt * 256;
  const int b = m0 >> 12;
  const int hbase = n0 >> 7;
  const int wm = wave >> 2, wn = wave & 3;
  const u16* Ag = g_xn + (size_t)m0 * 1024;
  const u16* wfQ = g_WF[0];

  char* A0 = smem;           // 32K
  char* A1 = smem + 32768;   // 32K ; epilogue: qs overlays 0..128K

  f32x4 zero = {0.f, 0.f, 0.f, 0.f};
  f32x4 acc[8][4];
#pragma unroll
  for (int i = 0; i < 8; i++)
#pragma unroll
    for (int j = 0; j < 4; j++) acc[i][j] = zero;

  // prologue
  stageA256(A0, Ag, 0, wave, lane);
  stageA256(A0, Ag, 1, wave, lane);
  asm volatile("s_waitcnt vmcnt(0)" ::: "memory");
  __builtin_amdgcn_s_barrier();

#pragma unroll 1
  for (int t = 0; t < 15; ++t) {
    const int p = t & 1;
    tile_1ph<true>(p ? A1 : A0, p ? A0 : A1, Ag + (t + 1) * 64, wfQ, hbase, t,
                   acc, wave, lane, wm, wn);
  }
  tile_1ph<false>(A1, A0, Ag, wfQ, hbase, 15, acc, wave, lane, wm, wn);

  // prefetch ALL ph2 B-fragments from global attT now; their L2 latency
  // hides under epilogue-1's exp/shuffle VALU work (no LDS needed).
  const int hl = wn >> 1;                      // head within the 2-head pair
  const int bhh = b * 8 + (n0 >> 7) + hl;
  const u16* attb = g_attT + ((size_t)bhh << 14);
  bf16x8 bpre[4][4];
#pragma unroll
  for (int ks = 0; ks < 4; ks++)
#pragma unroll
    for (int cf = 0; cf < 4; cf++) {
      const int l = (wn & 1) * 64 + cf * 16 + (lane & 15);  // out col (in head)
      bpre[ks][cf] = *(const bf16x8*)(attb + l * 128 + ks * 32 + (lane >> 4) * 8);
    }

  // epilogue-1: e = exp(q + bq) (clamped); write swizzled qs[tok][feat] into
  // the freed smem (slot = (feat>>3) ^ (tok&31), bijective per row); per-head
  // row-sums into zq4[wn][tok] (each wave's 64 cols lie in ONE head).
  u16* qs = (u16*)smem;
#pragma unroll
  for (int rf = 0; rf < 8; rf++)
#pragma unroll
    for (int r = 0; r < 4; r++) {
      const int tok = wm * 128 + rf * 16 + (lane >> 4) * 4 + r;
      float rs = 0.f;
#pragma unroll
      for (int cf = 0; cf < 4; cf++) {
        const int f = wn * 64 + cf * 16 + (lane & 15);
        const float e = __expf(fminf(acc[rf][cf][r] + bq[n0 + f], 30.0f));
        qs[tok * 256 + ((((f >> 3) ^ (tok & 31)) << 3) | (f & 7))] = f2b(e);
        rs += e;
      }
      rs += __shfl_xor(rs, 1);
      rs += __shfl_xor(rs, 2);
      rs += __shfl_xor(rs, 4);
      rs += __shfl_xor(rs, 8);
      if ((lane & 15) == 0) zq4[wn][tok] = rs;
    }
  __syncthreads();

  // phase 2: y[tok, col] = sum_d P[tok, hl*128+d] * attT[bhh][l*128 + d].
  // A-frags from swizzled qs (chunk = hl*16 + ks*4 + q); B from bpre regs.
  f32x4 acc2[8][4];
#pragma unroll
  for (int i = 0; i < 8; i++)
#pragma unroll
    for (int j = 0; j < 4; j++) acc2[i][j] = zero;

#pragma unroll
  for (int ks = 0; ks < 4; ks++) {
    bf16x8 af[8];
#pragma unroll
    for (int rf = 0; rf < 8; rf++) {
      const int tok = wm * 128 + rf * 16 + (lane & 15);
      af[rf] = *(const bf16x8*)&qs[tok * 256 +
          ((((hl << 4) + (ks << 2) + (lane >> 4)) ^ (tok & 31)) << 3)];
    }
#pragma unroll
    for (int rf = 0; rf < 8; rf++)
#pragma unroll
      for (int cf = 0; cf < 4; cf++)
        acc2[rf][cf] = __builtin_amdgcn_mfma_f32_16x16x32_bf16(
            af[rf], bpre[ks][cf], acc2[rf][cf], 0, 0, 0);
  }

  // epilogue-2: out = x + y / zq  (fp32)
#pragma unroll
  for (int rf = 0; rf < 8; rf++)
#pragma unroll
    for (int r = 0; r < 4; r++) {
      const int tok = wm * 128 + rf * 16 + (lane >> 4) * 4 + r;
      const float zq =
          fmaxf(zq4[hl * 2][tok] + zq4[hl * 2 + 1][tok], 1e-30f);
      const size_t n = (size_t)(m0 + tok);
#pragma unroll
      for (int cf = 0; cf < 4; cf++) {
        const int f = wn * 64 + cf * 16 + (lane & 15);
        const size_t idx = n * 1024 + n0 + f;
        out[idx] = x[idx] + acc2[rf][cf][r] / zq;
      }
    }
}

// ----------------------------------------------------------------- launch
extern "C" void kernel_launch(void* const* d_in, const int* in_sizes, int n_in,
                              void* d_out, int out_size, void* d_ws, size_t ws_size,
                              hipStream_t stream) {
  const float* x = (const float*)d_in[0];
  const float* mask = (const float*)d_in[1];
  const float* Wq = (const float*)d_in[2];
  const float* bq = (const float*)d_in[3];
  const float* Wk = (const float*)d_in[4];
  const float* bk = (const float*)d_in[5];
  const float* Wv = (const float*)d_in[6];
  const float* bv = (const float*)d_in[7];
  const float* gamma = (const float*)d_in[8];
  const float* beta = (const float*)d_in[9];
  float* out = (float*)d_out;
  (void)d_ws; (void)ws_size;

  prep_kernel<<<dim3(16384 + 3072), 256, 0, stream>>>(x, gamma, beta, Wq, Wk, Wv, mask);
  gemm_kva<<<dim3(512), 512, 0, stream>>>(bk, bv, mask);
  attnorm_kernel<<<dim3(32, 8), 256, 0, stream>>>();
  gemm_qy<<<dim3(256), 512, 0, stream>>>(bq, x, out);
}